// Round 1
// baseline (1625.236 us; speedup 1.0000x reference)
//
#include <hip/hip_runtime.h>
#include <stdint.h>

typedef __bf16 bf16;
typedef __bf16 bf16x8 __attribute__((ext_vector_type(8)));
typedef float f32x4 __attribute__((ext_vector_type(4)));

__device__ __forceinline__ float bfbits2f(uint32_t lo16) {
    uint32_t b = lo16 << 16;
    float f;
    __builtin_memcpy(&f, &b, 4);
    return f;
}

__device__ __forceinline__ uint32_t pack2bf(float a, float b) {
    uint32_t lo = __builtin_bit_cast(unsigned short, (bf16)a);
    uint32_t hi = __builtin_bit_cast(unsigned short, (bf16)b);
    return lo | (hi << 16);
}

__device__ __forceinline__ void gload_lds16(const void* g, void* l) {
    __builtin_amdgcn_global_load_lds((const __attribute__((address_space(1))) void*)g,
                                     (__attribute__((address_space(3))) void*)l, 16, 0, 0);
}

// ---- prep: W1T[h][f]=W1[f][h];  WcatT2[o][r*128+c]=weight[r][c][o], WcatT2[o][R*128+c]=root[c][o]
__global__ void k_prep(const float* __restrict__ W1, const float* __restrict__ weight,
                       const float* __restrict__ root, bf16* __restrict__ W1T,
                       bf16* __restrict__ WcatT2, int R, int ldt) {
    int total = 16384 * (R + 2);
    for (int i = blockIdx.x * blockDim.x + threadIdx.x; i < total; i += gridDim.x * blockDim.x) {
        if (i < 16384) {
            int f = i >> 7, h = i & 127;
            W1T[h * 128 + f] = (bf16)W1[f * 128 + h];
        } else {
            int j = i - 16384;
            int r = j >> 14, rem = j & 16383, c = rem >> 7, o = rem & 127;
            float v = (r < R) ? weight[(size_t)(r * 128 + c) * 128 + o] : root[c * 128 + o];
            WcatT2[(size_t)o * ldt + r * 128 + c] = (bf16)v;
        }
    }
}

// q[i] = sum_j W2[i][j]*Wo[j];  qc[128] = b2.Wo + bo
__global__ void k_qprep(const float* __restrict__ W2, const float* __restrict__ b2,
                        const float* __restrict__ Wo, const float* __restrict__ bo,
                        float* __restrict__ qc) {
    int i = threadIdx.x;
    float s = 0.f;
    for (int j = 0; j < 128; j++) s += W2[i * 128 + j] * Wo[j];
    qc[i] = s;
    if (i == 0) {
        float c = bo[0];
        for (int j = 0; j < 128; j++) c += b2[j] * Wo[j];
        qc[128] = c;
    }
}

// ---- CSR build over segments seg = r*N + dst (relation-major so a node-block's
// type-r edges are contiguous -> fused agg+GEMM kernel can phase over r) ----
__global__ void k_hist(const int* __restrict__ dst, const int* __restrict__ etype,
                       int* __restrict__ cnt, int E, int N) {
    for (int e = blockIdx.x * blockDim.x + threadIdx.x; e < E; e += gridDim.x * blockDim.x)
        atomicAdd(&cnt[etype[e] * N + dst[e]], 1);
}

__global__ __launch_bounds__(256) void k_scan_blk(const int* __restrict__ cnt, int* __restrict__ bsum, int M) {
    int i = blockIdx.x * 256 + threadIdx.x;
    int v = (i < M) ? cnt[i] : 0;
#pragma unroll
    for (int d = 1; d < 64; d <<= 1) v += __shfl_xor(v, d);
    __shared__ int ws[4];
    if ((threadIdx.x & 63) == 0) ws[threadIdx.x >> 6] = v;
    __syncthreads();
    if (threadIdx.x == 0) bsum[blockIdx.x] = ws[0] + ws[1] + ws[2] + ws[3];
}

// looped single-block exclusive scan over nb block sums (nb can exceed 256 now
// that the segment space is R*N = 400000)
__global__ __launch_bounds__(256) void k_scan_top(int* __restrict__ bsum, int nb) {
    __shared__ int s[256];
    __shared__ int carry;
    int t = threadIdx.x;
    if (t == 0) carry = 0;
    __syncthreads();
    for (int base = 0; base < nb; base += 256) {
        int i = base + t;
        int v = (i < nb) ? bsum[i] : 0;
        s[t] = v;
        __syncthreads();
#pragma unroll
        for (int d = 1; d < 256; d <<= 1) {
            int u = (t >= d) ? s[t - d] : 0;
            __syncthreads();
            s[t] += u;
            __syncthreads();
        }
        int excl = carry + s[t] - v;
        int tot = s[255];
        __syncthreads();
        if (i < nb) bsum[i] = excl;
        if (t == 0) carry += tot;
        __syncthreads();
    }
}

__global__ __launch_bounds__(256) void k_scan_apply(const int* __restrict__ cnt, const int* __restrict__ bsum,
                                                    int* __restrict__ row_off, int* __restrict__ cursor, int M) {
    int b = blockIdx.x, t = threadIdx.x;
    int i = b * 256 + t;
    int v = (i < M) ? cnt[i] : 0;
    int lane = t & 63, wid = t >> 6;
    int incl = v;
#pragma unroll
    for (int d = 1; d < 64; d <<= 1) {
        int u = __shfl_up(incl, d);
        if (lane >= d) incl += u;
    }
    __shared__ int ws[4];
    if (lane == 63) ws[wid] = incl;
    __syncthreads();
    int woff = 0;
    for (int wj = 0; wj < 4; wj++)
        if (wj < wid) woff += ws[wj];
    int excl = bsum[b] + woff + incl - v;
    if (i < M) {
        row_off[i] = excl;
        cursor[i] = excl;
        if (i == M - 1) row_off[M] = excl + v;
    }
}

// XCD-partitioned CSR fill (partition on seg range so each contiguous csr
// region is written from one XCD; lines fill fully before writeback).
// payload = (dst<<16)|src (requires N <= 65536).
__global__ void k_fill(const int* __restrict__ src, const int* __restrict__ dst,
                       const int* __restrict__ etype, int* __restrict__ cursor,
                       int* __restrict__ csr, int E, int N, int pbase) {
    int p = blockIdx.x & 7;
    int bg = blockIdx.x >> 3;
    int nchunk = gridDim.x >> 3;
    int chunk = (E + nchunk - 1) / nchunk;
    int beg = bg * chunk, end = min(beg + chunk, E);
    int lo = p * pbase, hi = lo + pbase;
    for (int e = beg + (int)threadIdx.x; e < end; e += blockDim.x) {
        int d = dst[e];
        int seg = etype[e] * N + d;
        if (seg >= lo && seg < hi) {
            int pos = atomicAdd(&cursor[seg], 1);
            csr[pos] = (int)(((uint32_t)d << 16) | (uint32_t)src[e]);
        }
    }
}

// ---- GEMM (layer 0): C[M x 128] = A_f32[M x 128] * B[128 x 128] (+bias), bf16 out
__global__ __launch_bounds__(256) void k_gemm0(const float* __restrict__ A, const bf16* __restrict__ BT,
                                               const float* __restrict__ bias, bf16* __restrict__ C, int M) {
    __shared__ bf16 sA[128 * 128];
    __shared__ bf16 sB[128 * 128];
    int tid = threadIdx.x;
    int m0 = blockIdx.x * 128;
#pragma unroll
    for (int i = 0; i < 8; i++) {
        int chunk = i * 256 + tid;
        int row = chunk >> 4, c16 = chunk & 15;
        int sw = ((c16 ^ (row & 7)) << 3);
        int gr = m0 + row;
        int4 va = {0, 0, 0, 0};
        if (gr < M) {
            const float* ap = A + (size_t)gr * 128 + (c16 << 3);
            float4 f0 = *reinterpret_cast<const float4*>(ap);
            float4 f1 = *reinterpret_cast<const float4*>(ap + 4);
            bf16 tmp[8] = {(bf16)f0.x, (bf16)f0.y, (bf16)f0.z, (bf16)f0.w,
                           (bf16)f1.x, (bf16)f1.y, (bf16)f1.z, (bf16)f1.w};
            __builtin_memcpy(&va, tmp, 16);
        }
        *reinterpret_cast<int4*>(&sA[row * 128 + sw]) = va;
        int4 vb = *reinterpret_cast<const int4*>(&BT[(size_t)row * 128 + (c16 << 3)]);
        *reinterpret_cast<int4*>(&sB[row * 128 + sw]) = vb;
    }
    __syncthreads();

    int lane = tid & 63, w = tid >> 6;
    int wm = (w >> 1) * 64, wn = (w & 1) * 64;
    int lr = lane & 15, lk = lane >> 4;
    f32x4 zero = {0.f, 0.f, 0.f, 0.f};
    f32x4 acc[4][4];
#pragma unroll
    for (int mi = 0; mi < 4; mi++)
#pragma unroll
        for (int ni = 0; ni < 4; ni++) acc[mi][ni] = zero;

#pragma unroll
    for (int kk = 0; kk < 4; kk++) {
        int c = (kk << 2) + lk;
        bf16x8 af[4], bfr[4];
#pragma unroll
        for (int mi = 0; mi < 4; mi++) {
            int r = wm + mi * 16 + lr;
            af[mi] = *reinterpret_cast<const bf16x8*>(&sA[r * 128 + ((c ^ (r & 7)) << 3)]);
        }
#pragma unroll
        for (int ni = 0; ni < 4; ni++) {
            int r = wn + ni * 16 + lr;
            bfr[ni] = *reinterpret_cast<const bf16x8*>(&sB[r * 128 + ((c ^ (r & 7)) << 3)]);
        }
#pragma unroll
        for (int mi = 0; mi < 4; mi++)
#pragma unroll
            for (int ni = 0; ni < 4; ni++)
                acc[mi][ni] = __builtin_amdgcn_mfma_f32_16x16x32_bf16(af[mi], bfr[ni], acc[mi][ni], 0, 0, 0);
    }

#pragma unroll
    for (int ni = 0; ni < 4; ni++) {
        int col = wn + ni * 16 + lr;
        float bia = bias[col];
#pragma unroll
        for (int mi = 0; mi < 4; mi++) {
#pragma unroll
            for (int j = 0; j < 4; j++) {
                int row = m0 + wm + mi * 16 + lk * 4 + j;
                if (row < M) C[(size_t)row * 128 + col] = (bf16)(acc[mi][ni][j] + bia);
            }
        }
    }
}

// ---- FUSED aggregation + per-relation GEMM + bias + BN-stats.
// Block = 64 output nodes, 256 threads (4 waves, wave w owns rows w*16..w*16+15).
// Per relation r: zero 64x128 f32 LDS tile -> edge-parallel scatter-add of
// gathered h[src] rows (ds_add_f32; csr range for (r, node-block) is contiguous
// because seg = r*N+dst) -> MFMA vs WcatT2 r-slice (B-frags straight from L2),
// converting f32->bf16 at fragment read. Root term staged as bf16 via
// global_load_lds. Eliminates the 102MB G tensor entirely (was 100MB write in
// k_agg2 + 102MB fetch in k_gemm2 per layer).
// sAgg is 16B-chunk XOR-swizzled: phys f32 idx = ((x>>2)^(row&7))<<2 | (x&3).
__global__ __launch_bounds__(256, 4) void k_aggmm(const bf16* __restrict__ h, const int* __restrict__ row_off,
                                                  const int* __restrict__ csr, const bf16* __restrict__ BT,
                                                  const float* __restrict__ bias, float* __restrict__ C,
                                                  float* __restrict__ stats, int N, int R, int ldt) {
    __shared__ float sAgg[64 * 128];  // 32 KB
    __shared__ float csum[128], csum2[128];
    int tid = threadIdx.x;
    int lane = tid & 63, w = tid >> 6;
    int lr = lane & 15, lk = lane >> 4;
    int n0 = blockIdx.x * 64;
    int nhi = min(n0 + 64, N);
    if (tid < 128) { csum[tid] = 0.f; csum2[tid] = 0.f; }
    int c0 = lane * 2;

    f32x4 zero4 = {0.f, 0.f, 0.f, 0.f};
    f32x4 acc[8];
#pragma unroll
    for (int ni = 0; ni < 8; ni++) acc[ni] = zero4;

    for (int r = 0; r < R; r++) {
        // zero tile
#pragma unroll
        for (int i = 0; i < 8; i++)
            *reinterpret_cast<f32x4*>(&sAgg[(i * 256 + tid) * 4]) = zero4;
        __syncthreads();
        // flat edge-parallel aggregation for relation r, nodes [n0, nhi)
        int e0 = row_off[r * N + n0];
        int e1 = row_off[r * N + nhi];
        int ne = e1 - e0;
        int chunk = (ne + 3) >> 2;
        int beg = e0 + w * chunk;
        int end = min(beg + chunk, e1);
        int e = beg;
        for (; e + 8 <= end; e += 8) {
            uint32_t pp[8], vv[8];
#pragma unroll
            for (int u = 0; u < 8; u++) pp[u] = (uint32_t)csr[e + u];
#pragma unroll
            for (int u = 0; u < 8; u++)
                vv[u] = *reinterpret_cast<const uint32_t*>(&h[(size_t)(pp[u] & 0xffffu) * 128 + c0]);
#pragma unroll
            for (int u = 0; u < 8; u++) {
                int dl = (int)(pp[u] >> 16) - n0;
                float* a = &sAgg[dl * 128 + ((((lane >> 1) ^ (dl & 7)) << 2) | (c0 & 3))];
                atomicAdd(a, bfbits2f(vv[u] & 0xffffu));
                atomicAdd(a + 1, bfbits2f(vv[u] >> 16));
            }
        }
        for (; e < end; e++) {
            uint32_t p = (uint32_t)csr[e];
            uint32_t v = *reinterpret_cast<const uint32_t*>(&h[(size_t)(p & 0xffffu) * 128 + c0]);
            int dl = (int)(p >> 16) - n0;
            float* a = &sAgg[dl * 128 + ((((lane >> 1) ^ (dl & 7)) << 2) | (c0 & 3))];
            atomicAdd(a, bfbits2f(v & 0xffffu));
            atomicAdd(a + 1, bfbits2f(v >> 16));
        }
        __syncthreads();
        // MFMA this r-slice: A = sAgg (f32 -> bf16 at read), B = WcatT2 cols r*128..
        int rr = (w << 4) + lr;
#pragma unroll
        for (int kk = 0; kk < 4; kk++) {
            int c = (kk << 2) + lk;           // 16-byte bf16 chunk index (8 k-elems)
            int ch0 = ((c << 1) ^ (rr & 7));  // two 16B f32 chunks back it
            int ch1 = ch0 ^ 1;
            f32x4 a0 = *reinterpret_cast<const f32x4*>(&sAgg[rr * 128 + (ch0 << 2)]);
            f32x4 a1 = *reinterpret_cast<const f32x4*>(&sAgg[rr * 128 + (ch1 << 2)]);
            bf16 tmp[8] = {(bf16)a0[0], (bf16)a0[1], (bf16)a0[2], (bf16)a0[3],
                           (bf16)a1[0], (bf16)a1[1], (bf16)a1[2], (bf16)a1[3]};
            bf16x8 af;
            __builtin_memcpy(&af, tmp, 16);
#pragma unroll
            for (int ni = 0; ni < 8; ni++) {
                int o = (ni << 4) + lr;
                bf16x8 bfrag = *reinterpret_cast<const bf16x8*>(&BT[(size_t)o * ldt + (r << 7) + (c << 3)]);
                acc[ni] = __builtin_amdgcn_mfma_f32_16x16x32_bf16(af, bfrag, acc[ni], 0, 0, 0);
            }
        }
        __syncthreads();  // before next phase's zeroing
    }

    // root phase: stage h tile as bf16 (reuse sAgg memory), standard swizzle
    bf16* sH = reinterpret_cast<bf16*>(sAgg);
#pragma unroll
    for (int i = 0; i < 4; i++) {
        int chunkid = i * 256 + tid;
        int row = chunkid >> 4, c16 = chunkid & 15;
        int sw = (c16 ^ (row & 7)) << 3;
        int gr = n0 + row;
        gr = gr < N ? gr : N - 1;  // clamp; dup rows masked at C-write
        gload_lds16(h + (size_t)gr * 128 + sw, &sH[chunkid * 8]);
    }
    asm volatile("s_waitcnt vmcnt(0)" ::: "memory");
    __syncthreads();
    {
        int rr = (w << 4) + lr;
#pragma unroll
        for (int kk = 0; kk < 4; kk++) {
            int c = (kk << 2) + lk;
            bf16x8 af = *reinterpret_cast<const bf16x8*>(&sH[rr * 128 + ((c ^ (rr & 7)) << 3)]);
#pragma unroll
            for (int ni = 0; ni < 8; ni++) {
                int o = (ni << 4) + lr;
                bf16x8 bfrag = *reinterpret_cast<const bf16x8*>(&BT[(size_t)o * ldt + (R << 7) + (c << 3)]);
                acc[ni] = __builtin_amdgcn_mfma_f32_16x16x32_bf16(af, bfrag, acc[ni], 0, 0, 0);
            }
        }
    }

    // epilogue: bias + conv write + fused BN stats
#pragma unroll
    for (int ni = 0; ni < 8; ni++) {
        int col = (ni << 4) + lr;
        float bia = bias[col];
        float s = 0.f, s2 = 0.f;
#pragma unroll
        for (int j = 0; j < 4; j++) {
            int row = n0 + (w << 4) + (lk << 2) + j;
            if (row < N) {
                float val = acc[ni][j] + bia;
                C[(size_t)row * 128 + col] = val;
                s += val;
                s2 += val * val;
            }
        }
        s += __shfl_xor(s, 16); s += __shfl_xor(s, 32);
        s2 += __shfl_xor(s2, 16); s2 += __shfl_xor(s2, 32);
        if (lk == 0) { atomicAdd(&csum[col], s); atomicAdd(&csum2[col], s2); }
    }
    __syncthreads();
    if (tid < 128) {
        atomicAdd(&stats[tid], csum[tid]);
        atomicAdd(&stats[128 + tid], csum2[tid]);
    }
}

// ---- finalize BN coefficients; also re-zeros stats for the next layer
__global__ void k_bnfin(float* __restrict__ stats, const float* __restrict__ gamma,
                        const float* __restrict__ beta, float* __restrict__ bnp, float invN) {
    int t = threadIdx.x;
    float mu = stats[t] * invN;
    float var = stats[128 + t] * invN - mu * mu;
    float sc = gamma[t] * rsqrtf(var + 1e-5f);
    bnp[t] = sc;
    bnp[128 + t] = beta[t] - mu * sc;
    stats[t] = 0.f;
    stats[128 + t] = 0.f;
}

// ---- BN + ReLU + cast to bf16 (layer 1) ----
__global__ void k_bnrelu(const float* __restrict__ conv, const float* __restrict__ bnp,
                         bf16* __restrict__ h, int N) {
    int total = N * 32;
    for (int i = blockIdx.x * blockDim.x + threadIdx.x; i < total; i += gridDim.x * blockDim.x) {
        int c4 = (i & 31) << 2;
        float4 v = *reinterpret_cast<const float4*>(&conv[(size_t)i * 4]);
        const float* vv = &v.x;
        uint64_t pk = 0;
#pragma unroll
        for (int j = 0; j < 4; j++) {
            int c = c4 + j;
            float val = fmaxf(vv[j] * bnp[c] + bnp[128 + c], 0.f);
            unsigned short us = __builtin_bit_cast(unsigned short, (bf16)val);
            pk |= (uint64_t)us << (16 * j);
        }
        *reinterpret_cast<uint64_t*>(&h[(size_t)i * 4]) = pk;
    }
}

// ---- layer 2: out[n] = sigmoid(relu(bn(conv[n])) . q + c), fused, f32 out ----
__global__ __launch_bounds__(256) void k_bnout(const float* __restrict__ conv, const float* __restrict__ bnp,
                                               const float* __restrict__ qc, float* __restrict__ out, int N) {
    int wi = threadIdx.x >> 6;
    int n = blockIdx.x * 4 + wi;
    if (n >= N) return;
    int lane = threadIdx.x & 63;
    int c0 = lane * 2;
    float2 v = *reinterpret_cast<const float2*>(&conv[(size_t)n * 128 + c0]);
    float v0 = fmaxf(v.x * bnp[c0] + bnp[128 + c0], 0.f);
    float v1 = fmaxf(v.y * bnp[c0 + 1] + bnp[128 + c0 + 1], 0.f);
    float s = v0 * qc[c0] + v1 * qc[c0 + 1];
#pragma unroll
    for (int d = 1; d < 64; d <<= 1) s += __shfl_xor(s, d);
    if (lane == 0) out[n] = 1.f / (1.f + expf(-(s + qc[128])));
}

extern "C" void kernel_launch(void* const* d_in, const int* in_sizes, int n_in,
                              void* d_out, int out_size, void* d_ws, size_t ws_size,
                              hipStream_t stream) {
    const float* x      = (const float*)d_in[0];
    const int*   ei     = (const int*)d_in[1];
    const int*   etype  = (const int*)d_in[2];
    const float* W1     = (const float*)d_in[3];
    const float* b1     = (const float*)d_in[4];
    const float* weight = (const float*)d_in[5];
    const float* root   = (const float*)d_in[6];
    const float* bias_c = (const float*)d_in[7];
    const float* gamma  = (const float*)d_in[8];
    const float* beta   = (const float*)d_in[9];
    const float* W2     = (const float*)d_in[10];
    const float* b2     = (const float*)d_in[11];
    const float* Wo     = (const float*)d_in[12];
    const float* bo     = (const float*)d_in[13];
    float* out = (float*)d_out;

    int H = in_sizes[4];            // 128
    int F = in_sizes[3] / H;        // 128
    int N = in_sizes[0] / F;        // 50000
    int E = in_sizes[2];            // 800000
    int R = in_sizes[5] / (H * H);  // 8
    int ldt = (R + 1) * H;          // 1152
    int M = R * N;                  // 400000 segments (seg = r*N + dst)

    const int* srcv = ei;
    const int* dstv = ei + E;

    char* p = (char*)d_ws;
    auto alloc = [&](size_t bytes) -> char* {
        char* r = p;
        p += (bytes + 255) & ~(size_t)255;
        return r;
    };
    bf16*  h       = (bf16*)alloc((size_t)N * H * 2);
    float* conv    = (float*)alloc((size_t)N * H * 4);
    bf16*  WcatT2  = (bf16*)alloc((size_t)ldt * H * 2);
    bf16*  W1T     = (bf16*)alloc((size_t)F * H * 2);
    float* qc      = (float*)alloc(129 * 4);
    int*   cnt     = (int*)alloc((size_t)M * 4);
    int*   row_off = (int*)alloc((size_t)(M + 1) * 4);
    int*   cursor  = (int*)alloc((size_t)M * 4);
    int*   csr     = (int*)alloc((size_t)E * 4);
    float* stats   = (float*)alloc(256 * 4);
    float* bnp     = (float*)alloc(256 * 4);
    int*   bsum    = (int*)alloc(2048 * 4);
    if ((size_t)(p - (char*)d_ws) > ws_size) return;

    int nb = (M + 255) / 256;   // 1563 (<= 2048 for N <= 65536, R <= 8)
    int pbase = (M + 7) / 8;    // seg-partition width for XCD-local csr fill

    hipMemsetAsync(cnt, 0, (size_t)M * 4, stream);
    hipMemsetAsync(stats, 0, 256 * 4, stream);
    k_prep<<<256, 256, 0, stream>>>(W1, weight, root, W1T, WcatT2, R, ldt);
    k_qprep<<<1, 128, 0, stream>>>(W2, b2, Wo, bo, qc);
    k_hist<<<1024, 256, 0, stream>>>(dstv, etype, cnt, E, N);
    k_scan_blk<<<nb, 256, 0, stream>>>(cnt, bsum, M);
    k_scan_top<<<1, 256, 0, stream>>>(bsum, nb);
    k_scan_apply<<<nb, 256, 0, stream>>>(cnt, bsum, row_off, cursor, M);
    k_fill<<<1024, 256, 0, stream>>>(srcv, dstv, etype, cursor, csr, E, N, pbase);

    int mb = (N + 127) / 128;
    k_gemm0<<<mb, 256, 0, stream>>>(x, W1T, b1, h, N);

    int ab = (N + 63) / 64;
    for (int l = 0; l < 2; l++) {
        k_aggmm<<<ab, 256, 0, stream>>>(h, row_off, csr, WcatT2, bias_c, conv, stats, N, R, ldt);
        k_bnfin<<<1, 128, 0, stream>>>(stats, gamma, beta, bnp, 1.f / (float)N);
        if (l == 0)
            k_bnrelu<<<2048, 256, 0, stream>>>(conv, bnp, h, N);
        else
            k_bnout<<<(N + 3) / 4, 256, 0, stream>>>(conv, bnp, qc, out, N);
    }
}

// Round 2
// 498.929 us; speedup vs baseline: 3.2575x; 3.2575x over previous
//
#include <hip/hip_runtime.h>
#include <stdint.h>

typedef __bf16 bf16;
typedef __bf16 bf16x8 __attribute__((ext_vector_type(8)));
typedef float f32x4 __attribute__((ext_vector_type(4)));

__device__ __forceinline__ float bfbits2f(uint32_t lo16) {
    uint32_t b = lo16 << 16;
    float f;
    __builtin_memcpy(&f, &b, 4);
    return f;
}

__device__ __forceinline__ uint32_t pack2bf(float a, float b) {
    uint32_t lo = __builtin_bit_cast(unsigned short, (bf16)a);
    uint32_t hi = __builtin_bit_cast(unsigned short, (bf16)b);
    return lo | (hi << 16);
}

// ---- prep: W1T[h][f]=W1[f][h];  WcatT2[o][r*128+c]=weight[r][c][o], WcatT2[o][R*128+c]=root[c][o]
__global__ void k_prep(const float* __restrict__ W1, const float* __restrict__ weight,
                       const float* __restrict__ root, bf16* __restrict__ W1T,
                       bf16* __restrict__ WcatT2, int R, int ldt) {
    int total = 16384 * (R + 2);
    for (int i = blockIdx.x * blockDim.x + threadIdx.x; i < total; i += gridDim.x * blockDim.x) {
        if (i < 16384) {
            int f = i >> 7, h = i & 127;
            W1T[h * 128 + f] = (bf16)W1[f * 128 + h];
        } else {
            int j = i - 16384;
            int r = j >> 14, rem = j & 16383, c = rem >> 7, o = rem & 127;
            float v = (r < R) ? weight[(size_t)(r * 128 + c) * 128 + o] : root[c * 128 + o];
            WcatT2[(size_t)o * ldt + r * 128 + c] = (bf16)v;
        }
    }
}

// q[i] = sum_j W2[i][j]*Wo[j];  qc[128] = b2.Wo + bo
__global__ void k_qprep(const float* __restrict__ W2, const float* __restrict__ b2,
                        const float* __restrict__ Wo, const float* __restrict__ bo,
                        float* __restrict__ qc) {
    int i = threadIdx.x;
    float s = 0.f;
    for (int j = 0; j < 128; j++) s += W2[i * 128 + j] * Wo[j];
    qc[i] = s;
    if (i == 0) {
        float c = bo[0];
        for (int j = 0; j < 128; j++) c += b2[j] * Wo[j];
        qc[128] = c;
    }
}

// ---- CSR build over segments seg = r*N + dst (relation-major; within a
// relation edges are grouped by ascending dst -> contiguous per node range) ----
__global__ void k_hist(const int* __restrict__ dst, const int* __restrict__ etype,
                       int* __restrict__ cnt, int E, int N) {
    for (int e = blockIdx.x * blockDim.x + threadIdx.x; e < E; e += gridDim.x * blockDim.x)
        atomicAdd(&cnt[etype[e] * N + dst[e]], 1);
}

__global__ __launch_bounds__(256) void k_scan_blk(const int* __restrict__ cnt, int* __restrict__ bsum, int M) {
    int i = blockIdx.x * 256 + threadIdx.x;
    int v = (i < M) ? cnt[i] : 0;
#pragma unroll
    for (int d = 1; d < 64; d <<= 1) v += __shfl_xor(v, d);
    __shared__ int ws[4];
    if ((threadIdx.x & 63) == 0) ws[threadIdx.x >> 6] = v;
    __syncthreads();
    if (threadIdx.x == 0) bsum[blockIdx.x] = ws[0] + ws[1] + ws[2] + ws[3];
}

// looped single-block exclusive scan over nb block sums
__global__ __launch_bounds__(256) void k_scan_top(int* __restrict__ bsum, int nb) {
    __shared__ int s[256];
    __shared__ int carry;
    int t = threadIdx.x;
    if (t == 0) carry = 0;
    __syncthreads();
    for (int base = 0; base < nb; base += 256) {
        int i = base + t;
        int v = (i < nb) ? bsum[i] : 0;
        s[t] = v;
        __syncthreads();
#pragma unroll
        for (int d = 1; d < 256; d <<= 1) {
            int u = (t >= d) ? s[t - d] : 0;
            __syncthreads();
            s[t] += u;
            __syncthreads();
        }
        int excl = carry + s[t] - v;
        int tot = s[255];
        __syncthreads();
        if (i < nb) bsum[i] = excl;
        if (t == 0) carry += tot;
        __syncthreads();
    }
}

__global__ __launch_bounds__(256) void k_scan_apply(const int* __restrict__ cnt, const int* __restrict__ bsum,
                                                    int* __restrict__ row_off, int* __restrict__ cursor, int M) {
    int b = blockIdx.x, t = threadIdx.x;
    int i = b * 256 + t;
    int v = (i < M) ? cnt[i] : 0;
    int lane = t & 63, wid = t >> 6;
    int incl = v;
#pragma unroll
    for (int d = 1; d < 64; d <<= 1) {
        int u = __shfl_up(incl, d);
        if (lane >= d) incl += u;
    }
    __shared__ int ws[4];
    if (lane == 63) ws[wid] = incl;
    __syncthreads();
    int woff = 0;
    for (int wj = 0; wj < 4; wj++)
        if (wj < wid) woff += ws[wj];
    int excl = bsum[b] + woff + incl - v;
    if (i < M) {
        row_off[i] = excl;
        cursor[i] = excl;
        if (i == M - 1) row_off[M] = excl + v;
    }
}

// XCD-partitioned CSR fill. payload = (dst<<16)|src (requires N <= 65536).
__global__ void k_fill(const int* __restrict__ src, const int* __restrict__ dst,
                       const int* __restrict__ etype, int* __restrict__ cursor,
                       int* __restrict__ csr, int E, int N, int pbase) {
    int p = blockIdx.x & 7;
    int bg = blockIdx.x >> 3;
    int nchunk = gridDim.x >> 3;
    int chunk = (E + nchunk - 1) / nchunk;
    int beg = bg * chunk, end = min(beg + chunk, E);
    int lo = p * pbase, hi = lo + pbase;
    for (int e = beg + (int)threadIdx.x; e < end; e += blockDim.x) {
        int d = dst[e];
        int seg = etype[e] * N + d;
        if (seg >= lo && seg < hi) {
            int pos = atomicAdd(&cursor[seg], 1);
            csr[pos] = (int)(((uint32_t)d << 16) | (uint32_t)src[e]);
        }
    }
}

// ---- GEMM (layer 0): C[M x 128] = A_f32[M x 128] * B[128 x 128] (+bias), bf16 out
__global__ __launch_bounds__(256) void k_gemm0(const float* __restrict__ A, const bf16* __restrict__ BT,
                                               const float* __restrict__ bias, bf16* __restrict__ C, int M) {
    __shared__ bf16 sA[128 * 128];
    __shared__ bf16 sB[128 * 128];
    int tid = threadIdx.x;
    int m0 = blockIdx.x * 128;
#pragma unroll
    for (int i = 0; i < 8; i++) {
        int chunk = i * 256 + tid;
        int row = chunk >> 4, c16 = chunk & 15;
        int sw = ((c16 ^ (row & 7)) << 3);
        int gr = m0 + row;
        int4 va = {0, 0, 0, 0};
        if (gr < M) {
            const float* ap = A + (size_t)gr * 128 + (c16 << 3);
            float4 f0 = *reinterpret_cast<const float4*>(ap);
            float4 f1 = *reinterpret_cast<const float4*>(ap + 4);
            bf16 tmp[8] = {(bf16)f0.x, (bf16)f0.y, (bf16)f0.z, (bf16)f0.w,
                           (bf16)f1.x, (bf16)f1.y, (bf16)f1.z, (bf16)f1.w};
            __builtin_memcpy(&va, tmp, 16);
        }
        *reinterpret_cast<int4*>(&sA[row * 128 + sw]) = va;
        int4 vb = *reinterpret_cast<const int4*>(&BT[(size_t)row * 128 + (c16 << 3)]);
        *reinterpret_cast<int4*>(&sB[row * 128 + sw]) = vb;
    }
    __syncthreads();

    int lane = tid & 63, w = tid >> 6;
    int wm = (w >> 1) * 64, wn = (w & 1) * 64;
    int lr = lane & 15, lk = lane >> 4;
    f32x4 zero = {0.f, 0.f, 0.f, 0.f};
    f32x4 acc[4][4];
#pragma unroll
    for (int mi = 0; mi < 4; mi++)
#pragma unroll
        for (int ni = 0; ni < 4; ni++) acc[mi][ni] = zero;

#pragma unroll
    for (int kk = 0; kk < 4; kk++) {
        int c = (kk << 2) + lk;
        bf16x8 af[4], bfr[4];
#pragma unroll
        for (int mi = 0; mi < 4; mi++) {
            int r = wm + mi * 16 + lr;
            af[mi] = *reinterpret_cast<const bf16x8*>(&sA[r * 128 + ((c ^ (r & 7)) << 3)]);
        }
#pragma unroll
        for (int ni = 0; ni < 4; ni++) {
            int r = wn + ni * 16 + lr;
            bfr[ni] = *reinterpret_cast<const bf16x8*>(&sB[r * 128 + ((c ^ (r & 7)) << 3)]);
        }
#pragma unroll
        for (int mi = 0; mi < 4; mi++)
#pragma unroll
            for (int ni = 0; ni < 4; ni++)
                acc[mi][ni] = __builtin_amdgcn_mfma_f32_16x16x32_bf16(af[mi], bfr[ni], acc[mi][ni], 0, 0, 0);
    }

#pragma unroll
    for (int ni = 0; ni < 4; ni++) {
        int col = wn + ni * 16 + lr;
        float bia = bias[col];
#pragma unroll
        for (int mi = 0; mi < 4; mi++) {
#pragma unroll
            for (int j = 0; j < 4; j++) {
                int row = m0 + wm + mi * 16 + lk * 4 + j;
                if (row < M) C[(size_t)row * 128 + col] = (bf16)(acc[mi][ni][j] + bia);
            }
        }
    }
}

// ---- FUSED aggregation + per-relation GEMM + bias + BN-stats, v2.
// Block = 64 nodes, 4 waves. WAVE-PRIVATE ROW OWNERSHIP: wave w exclusively
// owns sAgg rows [w*16,(w+1)*16). csr is relation-major AND dst-sorted within
// a relation, so wave w's edges for relation r are the contiguous range
// row_off[r*N+n0+w*16] .. row_off[r*N+n0+(w+1)*16]. Consequences vs v1:
//   - plain LDS += (no atomics, no flat-CAS risk)
//   - ZERO barriers in the phase loop (gather/frag-read/zero all own-rows);
//     waves free-run across phases -> no convoy, loads overlap MFMA
//   - all 40 row_off boundaries preloaded once (no dependent scalar loads)
//   - no launch-bounds VGPR cap (v1's 64-cap serialized the gather pipeline)
// A-frags: f32->bf16 at read. B-frags straight from L2-resident WcatT2.
// Root term reads h fragments directly from global (== v1's staged read).
// sAgg 16B-chunk XOR swizzle: phys f32 chunk = (logical chunk) ^ (row&7).
__global__ __launch_bounds__(256, 4) void k_aggmm(const bf16* __restrict__ h, const int* __restrict__ row_off,
                                                  const int* __restrict__ csr, const bf16* __restrict__ BT,
                                                  const float* __restrict__ bias, float* __restrict__ C,
                                                  float* __restrict__ stats, int N, int R, int ldt) {
    __shared__ float sAgg[64 * 128];  // 32 KB
    __shared__ float csum[128], csum2[128];
    __shared__ int sOff[48];
    int tid = threadIdx.x;
    int lane = tid & 63, w = tid >> 6;
    int lr = lane & 15, lk = lane >> 4;
    int n0 = blockIdx.x * 64;
    if (tid < 128) { csum[tid] = 0.f; csum2[tid] = 0.f; }
    // preload all wave-range boundaries: sOff[r*5+w] = row_off[r*N + min(n0+w*16, N)]
    int nOff = R * 5;
    if (tid < nOff) {
        int r = tid / 5, ww = tid - r * 5;
        int node = n0 + (ww << 4);
        node = node < N ? node : N;
        sOff[tid] = row_off[(size_t)r * N + node];
    }
    int c0 = lane * 2;
    int x = lane >> 1;   // logical 16B f32-chunk index of this lane's pair
    int lo2 = c0 & 3;    // position within chunk

    f32x4 zero4 = {0.f, 0.f, 0.f, 0.f};
    f32x4 acc[8];
#pragma unroll
    for (int ni = 0; ni < 8; ni++) acc[ni] = zero4;

    // zero own rows (wave-private; no barrier needed for sAgg, but sOff needs one)
    float* mine = &sAgg[w * 2048];
#pragma unroll
    for (int i = 0; i < 8; i++)
        *reinterpret_cast<f32x4*>(&mine[i * 256 + lane * 4]) = zero4;
    __syncthreads();  // sOff + csum visibility

    int rr = (w << 4) + lr;  // this lane's A-fragment row (owned by wave w)
    for (int r = 0; r < R; r++) {
        // ---- gather phase: plain += into own rows
        int beg = sOff[r * 5 + w];
        int end = sOff[r * 5 + w + 1];
        int e = beg;
        for (; e + 8 <= end; e += 8) {
            uint32_t pp[8], vv[8];
#pragma unroll
            for (int u = 0; u < 8; u++) pp[u] = (uint32_t)csr[e + u];
#pragma unroll
            for (int u = 0; u < 8; u++)
                vv[u] = *reinterpret_cast<const uint32_t*>(&h[(size_t)(pp[u] & 0xffffu) * 128 + c0]);
#pragma unroll
            for (int u = 0; u < 8; u++) {
                int dl = (int)(pp[u] >> 16) - n0;
                float* a = &sAgg[dl * 128 + (((x ^ (dl & 7)) << 2) | lo2)];
                a[0] += bfbits2f(vv[u] & 0xffffu);
                a[1] += bfbits2f(vv[u] >> 16);
            }
        }
        for (; e < end; e++) {
            uint32_t p = (uint32_t)csr[e];
            uint32_t v = *reinterpret_cast<const uint32_t*>(&h[(size_t)(p & 0xffffu) * 128 + c0]);
            int dl = (int)(p >> 16) - n0;
            float* a = &sAgg[dl * 128 + (((x ^ (dl & 7)) << 2) | lo2)];
            a[0] += bfbits2f(v & 0xffffu);
            a[1] += bfbits2f(v >> 16);
        }
        // ---- read own-row A-fragments (f32 -> bf16), then re-zero own rows
        bf16x8 afr[4];
#pragma unroll
        for (int kk = 0; kk < 4; kk++) {
            int c = (kk << 2) + lk;
            int ch0 = (c << 1) ^ (rr & 7);
            f32x4 a0 = *reinterpret_cast<const f32x4*>(&sAgg[rr * 128 + (ch0 << 2)]);
            f32x4 a1 = *reinterpret_cast<const f32x4*>(&sAgg[rr * 128 + ((ch0 ^ 1) << 2)]);
            bf16 tmp[8] = {(bf16)a0[0], (bf16)a0[1], (bf16)a0[2], (bf16)a0[3],
                           (bf16)a1[0], (bf16)a1[1], (bf16)a1[2], (bf16)a1[3]};
            __builtin_memcpy(&afr[kk], tmp, 16);
        }
#pragma unroll
        for (int i = 0; i < 8; i++)
            *reinterpret_cast<f32x4*>(&mine[i * 256 + lane * 4]) = zero4;
        // ---- MFMA vs WcatT2 r-slice (B from L2; overlaps next phase's gather)
#pragma unroll
        for (int kk = 0; kk < 4; kk++) {
            int c = (kk << 2) + lk;
#pragma unroll
            for (int ni = 0; ni < 8; ni++) {
                int o = (ni << 4) + lr;
                bf16x8 bfrag = *reinterpret_cast<const bf16x8*>(&BT[(size_t)o * ldt + (r << 7) + (c << 3)]);
                acc[ni] = __builtin_amdgcn_mfma_f32_16x16x32_bf16(afr[kk], bfrag, acc[ni], 0, 0, 0);
            }
        }
    }

    // ---- root phase: A-fragments straight from h (== staged-swizzle read)
    {
        int grow = n0 + rr;
        grow = grow < N ? grow : N - 1;  // clamp; dup rows masked at C-write
#pragma unroll
        for (int kk = 0; kk < 4; kk++) {
            int c = (kk << 2) + lk;
            bf16x8 af = *reinterpret_cast<const bf16x8*>(&h[(size_t)grow * 128 + (c << 3)]);
#pragma unroll
            for (int ni = 0; ni < 8; ni++) {
                int o = (ni << 4) + lr;
                bf16x8 bfrag = *reinterpret_cast<const bf16x8*>(&BT[(size_t)o * ldt + (R << 7) + (c << 3)]);
                acc[ni] = __builtin_amdgcn_mfma_f32_16x16x32_bf16(af, bfrag, acc[ni], 0, 0, 0);
            }
        }
    }

    // ---- epilogue: bias + conv write + fused BN stats
#pragma unroll
    for (int ni = 0; ni < 8; ni++) {
        int col = (ni << 4) + lr;
        float bia = bias[col];
        float s = 0.f, s2 = 0.f;
#pragma unroll
        for (int j = 0; j < 4; j++) {
            int row = n0 + (w << 4) + (lk << 2) + j;
            if (row < N) {
                float val = acc[ni][j] + bia;
                C[(size_t)row * 128 + col] = val;
                s += val;
                s2 += val * val;
            }
        }
        s += __shfl_xor(s, 16); s += __shfl_xor(s, 32);
        s2 += __shfl_xor(s2, 16); s2 += __shfl_xor(s2, 32);
        if (lk == 0) { atomicAdd(&csum[col], s); atomicAdd(&csum2[col], s2); }
    }
    __syncthreads();
    if (tid < 128) {
        atomicAdd(&stats[tid], csum[tid]);
        atomicAdd(&stats[128 + tid], csum2[tid]);
    }
}

// ---- finalize BN coefficients; also re-zeros stats for the next layer
__global__ void k_bnfin(float* __restrict__ stats, const float* __restrict__ gamma,
                        const float* __restrict__ beta, float* __restrict__ bnp, float invN) {
    int t = threadIdx.x;
    float mu = stats[t] * invN;
    float var = stats[128 + t] * invN - mu * mu;
    float sc = gamma[t] * rsqrtf(var + 1e-5f);
    bnp[t] = sc;
    bnp[128 + t] = beta[t] - mu * sc;
    stats[t] = 0.f;
    stats[128 + t] = 0.f;
}

// ---- BN + ReLU + cast to bf16 (layer 1) ----
__global__ void k_bnrelu(const float* __restrict__ conv, const float* __restrict__ bnp,
                         bf16* __restrict__ h, int N) {
    int total = N * 32;
    for (int i = blockIdx.x * blockDim.x + threadIdx.x; i < total; i += gridDim.x * blockDim.x) {
        int c4 = (i & 31) << 2;
        float4 v = *reinterpret_cast<const float4*>(&conv[(size_t)i * 4]);
        const float* vv = &v.x;
        uint64_t pk = 0;
#pragma unroll
        for (int j = 0; j < 4; j++) {
            int c = c4 + j;
            float val = fmaxf(vv[j] * bnp[c] + bnp[128 + c], 0.f);
            unsigned short us = __builtin_bit_cast(unsigned short, (bf16)val);
            pk |= (uint64_t)us << (16 * j);
        }
        *reinterpret_cast<uint64_t*>(&h[(size_t)i * 4]) = pk;
    }
}

// ---- layer 2: out[n] = sigmoid(relu(bn(conv[n])) . q + c), fused, f32 out ----
__global__ __launch_bounds__(256) void k_bnout(const float* __restrict__ conv, const float* __restrict__ bnp,
                                               const float* __restrict__ qc, float* __restrict__ out, int N) {
    int wi = threadIdx.x >> 6;
    int n = blockIdx.x * 4 + wi;
    if (n >= N) return;
    int lane = threadIdx.x & 63;
    int c0 = lane * 2;
    float2 v = *reinterpret_cast<const float2*>(&conv[(size_t)n * 128 + c0]);
    float v0 = fmaxf(v.x * bnp[c0] + bnp[128 + c0], 0.f);
    float v1 = fmaxf(v.y * bnp[c0 + 1] + bnp[128 + c0 + 1], 0.f);
    float s = v0 * qc[c0] + v1 * qc[c0 + 1];
#pragma unroll
    for (int d = 1; d < 64; d <<= 1) s += __shfl_xor(s, d);
    if (lane == 0) out[n] = 1.f / (1.f + expf(-(s + qc[128])));
}

extern "C" void kernel_launch(void* const* d_in, const int* in_sizes, int n_in,
                              void* d_out, int out_size, void* d_ws, size_t ws_size,
                              hipStream_t stream) {
    const float* x      = (const float*)d_in[0];
    const int*   ei     = (const int*)d_in[1];
    const int*   etype  = (const int*)d_in[2];
    const float* W1     = (const float*)d_in[3];
    const float* b1     = (const float*)d_in[4];
    const float* weight = (const float*)d_in[5];
    const float* root   = (const float*)d_in[6];
    const float* bias_c = (const float*)d_in[7];
    const float* gamma  = (const float*)d_in[8];
    const float* beta   = (const float*)d_in[9];
    const float* W2     = (const float*)d_in[10];
    const float* b2     = (const float*)d_in[11];
    const float* Wo     = (const float*)d_in[12];
    const float* bo     = (const float*)d_in[13];
    float* out = (float*)d_out;

    int H = in_sizes[4];            // 128
    int F = in_sizes[3] / H;        // 128
    int N = in_sizes[0] / F;        // 50000
    int E = in_sizes[2];            // 800000
    int R = in_sizes[5] / (H * H);  // 8
    int ldt = (R + 1) * H;          // 1152
    int M = R * N;                  // 400000 segments (seg = r*N + dst)

    const int* srcv = ei;
    const int* dstv = ei + E;

    char* p = (char*)d_ws;
    auto alloc = [&](size_t bytes) -> char* {
        char* r = p;
        p += (bytes + 255) & ~(size_t)255;
        return r;
    };
    bf16*  h       = (bf16*)alloc((size_t)N * H * 2);
    float* conv    = (float*)alloc((size_t)N * H * 4);
    bf16*  WcatT2  = (bf16*)alloc((size_t)ldt * H * 2);
    bf16*  W1T     = (bf16*)alloc((size_t)F * H * 2);
    float* qc      = (float*)alloc(129 * 4);
    int*   cnt     = (int*)alloc((size_t)M * 4);
    int*   row_off = (int*)alloc((size_t)(M + 1) * 4);
    int*   cursor  = (int*)alloc((size_t)M * 4);
    int*   csr     = (int*)alloc((size_t)E * 4);
    float* stats   = (float*)alloc(256 * 4);
    float* bnp     = (float*)alloc(256 * 4);
    int*   bsum    = (int*)alloc(2048 * 4);
    if ((size_t)(p - (char*)d_ws) > ws_size) return;

    int nb = (M + 255) / 256;   // 1563 (<= 2048 for N <= 65536, R <= 8)
    int pbase = (M + 7) / 8;    // seg-partition width for XCD-local csr fill

    hipMemsetAsync(cnt, 0, (size_t)M * 4, stream);
    hipMemsetAsync(stats, 0, 256 * 4, stream);
    k_prep<<<256, 256, 0, stream>>>(W1, weight, root, W1T, WcatT2, R, ldt);
    k_qprep<<<1, 128, 0, stream>>>(W2, b2, Wo, bo, qc);
    k_hist<<<1024, 256, 0, stream>>>(dstv, etype, cnt, E, N);
    k_scan_blk<<<nb, 256, 0, stream>>>(cnt, bsum, M);
    k_scan_top<<<1, 256, 0, stream>>>(bsum, nb);
    k_scan_apply<<<nb, 256, 0, stream>>>(cnt, bsum, row_off, cursor, M);
    k_fill<<<1024, 256, 0, stream>>>(srcv, dstv, etype, cursor, csr, E, N, pbase);

    int mb = (N + 127) / 128;
    k_gemm0<<<mb, 256, 0, stream>>>(x, W1T, b1, h, N);

    int ab = (N + 63) / 64;
    for (int l = 0; l < 2; l++) {
        k_aggmm<<<ab, 256, 0, stream>>>(h, row_off, csr, WcatT2, bias_c, conv, stats, N, R, ldt);
        k_bnfin<<<1, 128, 0, stream>>>(stats, gamma, beta, bnp, 1.f / (float)N);
        if (l == 0)
            k_bnrelu<<<2048, 256, 0, stream>>>(conv, bnp, h, N);
        else
            k_bnout<<<(N + 3) / 4, 256, 0, stream>>>(conv, bnp, qc, out, N);
    }
}